// Round 2
// baseline (12776.266 us; speedup 1.0000x reference)
//
#include <hip/hip_runtime.h>

#define NTOK 65536
#define DDIM 512
#define HDIM 1024
#define NEXP 8
#define PROJ 256
#define CAP  16384
#define NSLOT (2*NTOK)
#define TCHUNK 16384
#define LOG100 4.605170185988091f

// ---------- helpers ----------
__device__ inline float bf2f(unsigned short u){
    union { float f; unsigned int i; } c; c.i = ((unsigned int)u) << 16; return c.f;
}
__device__ inline unsigned short f2bf(float f){
    union { float f; unsigned int i; } c; c.f = f;
    unsigned int x = c.i;
    return (unsigned short)((x + 0x7fffu + ((x >> 16) & 1u)) >> 16); // RTNE
}
__device__ inline void loadA4(const float* p, float v[4]){
    const float4 f = *(const float4*)p; v[0]=f.x; v[1]=f.y; v[2]=f.z; v[3]=f.w;
}
__device__ inline void loadA4(const unsigned short* p, float v[4]){
    ushort4 u = *(const ushort4*)p;
    v[0]=bf2f(u.x); v[1]=bf2f(u.y); v[2]=bf2f(u.z); v[3]=bf2f(u.w);
}
__device__ inline float wred(float v){
    #pragma unroll
    for (int o = 32; o > 0; o >>= 1) v += __shfl_xor(v, o, 64);
    return v;
}

__global__ void zero_k(float4* __restrict__ p){
    p[(long)blockIdx.x * 256 + threadIdx.x] = float4{0.f, 0.f, 0.f, 0.f};
}

// ---------- normalize sim columns ----------
__global__ void simn_k(const float* __restrict__ sim, float* __restrict__ simn){
    __shared__ float red[256];
    int j = threadIdx.x;
    for (int e = 0; e < NEXP; e++){
        float v = sim[j*NEXP + e];
        red[j] = v*v;
        __syncthreads();
        for (int s = 128; s > 0; s >>= 1){
            if (j < s) red[j] += red[j + s];
            __syncthreads();
        }
        float nrm = sqrtf(red[0]) + 1e-12f;
        __syncthreads();
        simn[j*NEXP + e] = v / nrm;
    }
}

// ---------- generic 128x128x8 fp32 GEMM ----------
// OMODE: 0 = f32 store, 1 = bf16 store, 2 = scatter-atomicAdd into out
template<typename TA, bool RELU, bool GATHER, int OMODE, bool EARLY>
__global__ __launch_bounds__(256)
void gemm_k(const TA* __restrict__ A, const float* __restrict__ B,
            const float* __restrict__ bias, float* __restrict__ Cout,
            int M, int Kd, int Nd,
            const int* __restrict__ rowidx,  // GATHER: input-row gather list
            const int* __restrict__ otok,    // OMODE==2: output token per row
            const float* __restrict__ gs,    // OMODE==2: gate weight per row
            const int* __restrict__ cntp, int cnti)
{
    const int row0 = blockIdx.y * 128, col0 = blockIdx.x * 128;
    int limit = M;
    if (EARLY){
        limit = cntp[cnti];
        if (limit > M) limit = M;
        if (row0 >= limit) return;
    }

    __shared__ float As[8][128];
    __shared__ float Bs[8][128];

    const int t  = threadIdx.x;
    const int am = t >> 1, ak = (t & 1) * 4;
    const int bk = t >> 5, bn = (t & 31) * 4;
    long asrc;
    {
        int arow = row0 + am;
        if (GATHER){
            int gi = (arow < limit) ? rowidx[arow] : 0;
            asrc = (long)gi * Kd;
        } else {
            asrc = (long)arow * Kd;
        }
    }
    const int tm = (t & 15) * 8, tn = (t >> 4) * 8;
    float acc[8][8];
    #pragma unroll
    for (int i = 0; i < 8; i++)
        #pragma unroll
        for (int j = 0; j < 8; j++) acc[i][j] = 0.f;

    for (int k0 = 0; k0 < Kd; k0 += 8){
        __syncthreads();
        float av[4];
        loadA4(A + asrc + k0 + ak, av);
        #pragma unroll
        for (int j = 0; j < 4; j++) As[ak + j][am] = av[j];
        float4 bv = *(const float4*)(B + (long)(k0 + bk) * Nd + col0 + bn);
        *(float4*)&Bs[bk][bn] = bv;
        __syncthreads();
        #pragma unroll
        for (int kk = 0; kk < 8; kk++){
            float a[8], b[8];
            *(float4*)(a)   = *(const float4*)&As[kk][tm];
            *(float4*)(a+4) = *(const float4*)&As[kk][tm+4];
            *(float4*)(b)   = *(const float4*)&Bs[kk][tn];
            *(float4*)(b+4) = *(const float4*)&Bs[kk][tn+4];
            #pragma unroll
            for (int i = 0; i < 8; i++)
                #pragma unroll
                for (int j = 0; j < 8; j++)
                    acc[i][j] = fmaf(a[i], b[j], acc[i][j]);
        }
    }
    float bb[8];
    #pragma unroll
    for (int j = 0; j < 8; j++) bb[j] = bias[col0 + tn + j];
    #pragma unroll
    for (int i = 0; i < 8; i++){
        int r = row0 + tm + i;
        float v[8];
        #pragma unroll
        for (int j = 0; j < 8; j++){
            v[j] = acc[i][j] + bb[j];
            if (RELU) v[j] = fmaxf(v[j], 0.f);
        }
        if (OMODE == 0){
            float* cp = Cout + (long)r * Nd + col0 + tn;
            float4 f0; f0.x=v[0]; f0.y=v[1]; f0.z=v[2]; f0.w=v[3];
            float4 f1; f1.x=v[4]; f1.y=v[5]; f1.z=v[6]; f1.w=v[7];
            *(float4*)cp = f0; *(float4*)(cp + 4) = f1;
        } else if (OMODE == 1){
            unsigned short* cp = (unsigned short*)Cout + (long)r * Nd + col0 + tn;
            ushort4 u0; u0.x=f2bf(v[0]); u0.y=f2bf(v[1]); u0.z=f2bf(v[2]); u0.w=f2bf(v[3]);
            ushort4 u1; u1.x=f2bf(v[4]); u1.y=f2bf(v[5]); u1.z=f2bf(v[6]); u1.w=f2bf(v[7]);
            *(ushort4*)cp = u0; *(ushort4*)(cp + 4) = u1;
        } else {
            if (r < limit){
                int tk = otok[r];
                float g = gs[r];
                float* op = Cout + (long)tk * DDIM + col0 + tn;
                #pragma unroll
                for (int j = 0; j < 8; j++) atomicAdd(op + j, v[j] * g);
            }
        }
    }
}

// ---------- gate: one wave per token ----------
__global__ __launch_bounds__(256)
void gate_k(const float* __restrict__ P, const float* __restrict__ simn,
            const float* __restrict__ temp, int mode, const int* __restrict__ label,
            int n0, int* __restrict__ idx, float* __restrict__ gw)
{
    int gtid = blockIdx.x * 256 + threadIdx.x;
    int local = gtid >> 6, lane = gtid & 63;
    int n = n0 + local;
    const float* p = P + (long)local * PROJ;
    float v[4];
    #pragma unroll
    for (int r = 0; r < 4; r++) v[r] = p[lane + 64*r];
    float ss = v[0]*v[0] + v[1]*v[1] + v[2]*v[2] + v[3]*v[3];
    float dots[8];
    #pragma unroll
    for (int e = 0; e < 8; e++){
        float d = 0.f;
        #pragma unroll
        for (int r = 0; r < 4; r++) d += v[r] * simn[(lane + 64*r)*NEXP + e];
        dots[e] = d;
    }
    ss = wred(ss);
    #pragma unroll
    for (int e = 0; e < 8; e++) dots[e] = wred(dots[e]);
    if (lane == 0){
        float scale = expf(fminf(temp[0], LOG100));
        float inv = scale / (sqrtf(ss) + 1e-12f);
        float l[8], mx = -1e30f;
        #pragma unroll
        for (int e = 0; e < 8; e++){ l[e] = dots[e] * inv; mx = fmaxf(mx, l[e]); }
        float g[8], s = 0.f;
        #pragma unroll
        for (int e = 0; e < 8; e++){ g[e] = expf(l[e] - mx); s += g[e]; }
        #pragma unroll
        for (int e = 0; e < 8; e++) g[e] /= s;
        int e0 = 0; float b0 = g[0];
        #pragma unroll
        for (int e = 1; e < 8; e++) if (g[e] > b0){ b0 = g[e]; e0 = e; }
        int e1 = (e0 == 0) ? 1 : 0; float b1v = g[e1];
        #pragma unroll
        for (int e = 0; e < 8; e++) if (e != e0 && g[e] > b1v){ b1v = g[e]; e1 = e; }
        float maskv = (mode == 0) ? 1.f : ((label[n] == mode - 1) ? 1.f : 0.f);
        float s2 = b0 + b1v + 1e-9f;
        gw[2*n]   = b0 / s2 * maskv;
        gw[2*n+1] = b1v / s2 * maskv;
        idx[2*n]   = e0;
        idx[2*n+1] = e1;
    }
}

// ---------- ranking phase 1: per-block expert counts ----------
__global__ __launch_bounds__(1024)
void rank_count_k(const int* __restrict__ idx, const int* __restrict__ label, int mode,
                  int* __restrict__ bcnt)
{
    __shared__ int c[NEXP];
    int t = threadIdx.x;
    if (t < NEXP) c[t] = 0;
    __syncthreads();
    int s = blockIdx.x * 1024 + t;
    int n = s >> 1;
    int e = idx[s];
    bool valid = (mode == 0) || (label[n] == mode - 1);
    if (valid) atomicAdd(&c[e], 1);
    __syncthreads();
    if (t < NEXP) bcnt[blockIdx.x * NEXP + t] = c[t];
}

// ---------- ranking phase 2: exclusive scan over blocks ----------
__global__ void rank_scan_k(const int* __restrict__ bcnt, int* __restrict__ boff,
                            int* __restrict__ cntk)
{
    int e = threadIdx.x;
    if (e < NEXP){
        int run = 0;
        for (int b = 0; b < NSLOT/1024; b++){
            boff[b * NEXP + e] = run;
            run += bcnt[b * NEXP + e];
        }
        cntk[e] = run < CAP ? run : CAP;
    }
}

// ---------- ranking phase 3: assign positions, emit tok + gate per slot ----------
__global__ __launch_bounds__(1024)
void rank_assign_k(const int* __restrict__ idx, const int* __restrict__ label, int mode,
                   const int* __restrict__ boff, const float* __restrict__ gw,
                   const float* __restrict__ dscale, int use_scale,
                   int* __restrict__ tok_of, float* __restrict__ gs_of)
{
    __shared__ int wcnt[16][NEXP];
    __shared__ int woff[16][NEXP];
    int t = threadIdx.x;
    int s = blockIdx.x * 1024 + t;
    int n = s >> 1;
    int e = idx[s];
    bool valid = (mode == 0) || (label[n] == mode - 1);
    int w = t >> 6, lane = t & 63;
    unsigned long long lt = (lane == 0) ? 0ull : ((1ull << lane) - 1ull);
    int myrank = 0;
    #pragma unroll
    for (int ei = 0; ei < NEXP; ei++){
        unsigned long long bal = __ballot(valid && (e == ei));
        if (ei == e) myrank = __popcll(bal & lt);
        if (lane == 0) wcnt[w][ei] = __popcll(bal);
    }
    __syncthreads();
    if (t < NEXP){
        int run = boff[blockIdx.x * NEXP + t];
        for (int w2 = 0; w2 < 16; w2++){
            woff[w2][t] = run;
            run += wcnt[w2][t];
        }
    }
    __syncthreads();
    int pos = woff[w][e] + myrank;
    bool keep = valid && (pos < CAP);
    if (keep){
        float scale = use_scale ? dscale[0] : 1.f;
        tok_of[e * CAP + pos] = n;
        gs_of[e * CAP + pos] = gw[s] * scale;
    }
}

extern "C" void kernel_launch(void* const* d_in, const int* in_sizes, int n_in,
                              void* d_out, int out_size, void* d_ws, size_t ws_size,
                              hipStream_t stream)
{
    (void)in_sizes; (void)n_in; (void)out_size;
    const float* x      = (const float*)d_in[0];
    const int*   label  = (const int*)  d_in[1];
    const float* dscale = (const float*)d_in[2];
    float* out = (float*)d_out;

    // Workspace layout (~35 MB total):
    //  [0, 32MB): big region. P chunk (16 MB, f32 [TCHUNK,PROJ]) during gate phase;
    //             reused as h (32 MB, bf16 [CAP,HDIM], one expert) during FFN phase.
    //  [32MB, +): small buffers.
    const size_t BIG = 33554432L;
    size_t need = BIG + (size_t)PROJ*NEXP*4 + (size_t)NSLOT*4*2 +
                  (size_t)NEXP*CAP*4*2 + (size_t)(NSLOT/1024)*NEXP*4*2 + 256;
    if (ws_size < need) return;  // clean failure (absmax ~ref magnitude), not a fault

    char* ws = (char*)d_ws;
    float*          P  = (float*)ws;
    unsigned short* h  = (unsigned short*)ws;
    char* sm = ws + BIG;
    float* simn  = (float*)sm;  sm += PROJ*NEXP*4;
    int*   idx   = (int*)sm;    sm += (size_t)NSLOT*4;
    float* gw    = (float*)sm;  sm += (size_t)NSLOT*4;
    int*   tok   = (int*)sm;    sm += (size_t)NEXP*CAP*4;
    float* gslot = (float*)sm;  sm += (size_t)NEXP*CAP*4;
    int*   bcnt  = (int*)sm;    sm += (size_t)(NSLOT/1024)*NEXP*4;
    int*   boff  = (int*)sm;    sm += (size_t)(NSLOT/1024)*NEXP*4;
    int*   cntk  = (int*)sm;    sm += 64;

    // out = 0
    zero_k<<<dim3((NTOK*DDIM/4)/256), dim3(256), 0, stream>>>((float4*)out);

    for (int m = 0; m < 3; m++){
        const float* Wp   = (const float*)d_in[3 + 8*m + 0];
        const float* bp   = (const float*)d_in[3 + 8*m + 1];
        const float* sim  = (const float*)d_in[3 + 8*m + 2];
        const float* temp = (const float*)d_in[3 + 8*m + 3];
        const float* W1   = (const float*)d_in[3 + 8*m + 4];
        const float* b1   = (const float*)d_in[3 + 8*m + 5];
        const float* W2   = (const float*)d_in[3 + 8*m + 6];
        const float* b2   = (const float*)d_in[3 + 8*m + 7];

        simn_k<<<dim3(1), dim3(256), 0, stream>>>(sim, simn);

        // projection + gate, in token chunks (P region reused per chunk)
        for (int c = 0; c < NTOK / TCHUNK; c++){
            gemm_k<float, false, false, 0, false>
                <<<dim3(PROJ/128, TCHUNK/128), 256, 0, stream>>>(
                    x + (long)c*TCHUNK*DDIM, Wp, bp, P,
                    TCHUNK, DDIM, PROJ, nullptr, nullptr, nullptr, nullptr, 0);
            gate_k<<<dim3(TCHUNK/4), dim3(256), 0, stream>>>(
                P, simn, temp, m, label, c*TCHUNK, idx, gw);
        }

        rank_count_k<<<dim3(NSLOT/1024), dim3(1024), 0, stream>>>(idx, label, m, bcnt);
        rank_scan_k<<<dim3(1), dim3(64), 0, stream>>>(bcnt, boff, cntk);
        rank_assign_k<<<dim3(NSLOT/1024), dim3(1024), 0, stream>>>(
            idx, label, m, boff, gw, dscale, (m > 0) ? 1 : 0, tok, gslot);

        // per-expert FFN: h = relu(gather(x)@W1+b1) (bf16), then scatter(h@W2+b2)
        for (int e = 0; e < NEXP; e++){
            gemm_k<float, true, true, 1, true>
                <<<dim3(HDIM/128, CAP/128), 256, 0, stream>>>(
                    x, W1 + (long)e*DDIM*HDIM, b1 + (long)e*HDIM, (float*)h,
                    CAP, DDIM, HDIM, tok + (long)e*CAP, nullptr, nullptr, cntk, e);
            gemm_k<unsigned short, false, false, 2, true>
                <<<dim3(DDIM/128, CAP/128), 256, 0, stream>>>(
                    h, W2 + (long)e*HDIM*DDIM, b2 + (long)e*DDIM, out,
                    CAP, HDIM, DDIM, nullptr, tok + (long)e*CAP, gslot + (long)e*CAP,
                    cntk, e);
        }
    }
}

// Round 3
// 3636.517 us; speedup vs baseline: 3.5133x; 3.5133x over previous
//
#include <hip/hip_runtime.h>

#define NTOK 65536
#define DDIM 512
#define HDIM 1024
#define NEXP 8
#define PROJ 256
#define CAP  16384
#define NSLOT (2*NTOK)
#define TCHUNK 16384
#define LOG100 4.605170185988091f

typedef __attribute__((ext_vector_type(8))) short bf16x8;
typedef __attribute__((ext_vector_type(4))) short short4v;
typedef __attribute__((ext_vector_type(4))) float f32x4;

// ---------- helpers ----------
__device__ inline float bf2f(unsigned short u){
    union { float f; unsigned int i; } c; c.i = ((unsigned int)u) << 16; return c.f;
}
__device__ inline unsigned short f2bf(float f){
    union { float f; unsigned int i; } c; c.f = f;
    unsigned int x = c.i;
    return (unsigned short)((x + 0x7fffu + ((x >> 16) & 1u)) >> 16); // RTNE
}
__device__ inline float wred(float v){
    #pragma unroll
    for (int o = 32; o > 0; o >>= 1) v += __shfl_xor(v, o, 64);
    return v;
}

__global__ void zero_k(float4* __restrict__ p){
    p[(long)blockIdx.x * 256 + threadIdx.x] = float4{0.f, 0.f, 0.f, 0.f};
}

// ---------- fp32 -> bf16 bulk convert (weights) ----------
__global__ void cvt_k(const float4* __restrict__ src, ushort4* __restrict__ dst, int n4){
    int i = blockIdx.x * 256 + threadIdx.x;
    if (i < n4){
        float4 f = src[i];
        ushort4 u; u.x = f2bf(f.x); u.y = f2bf(f.y); u.z = f2bf(f.z); u.w = f2bf(f.w);
        dst[i] = u;
    }
}

// ---------- normalize sim columns ----------
__global__ void simn_k(const float* __restrict__ sim, float* __restrict__ simn){
    __shared__ float red[256];
    int j = threadIdx.x;
    for (int e = 0; e < NEXP; e++){
        float v = sim[j*NEXP + e];
        red[j] = v*v;
        __syncthreads();
        for (int s = 128; s > 0; s >>= 1){
            if (j < s) red[j] += red[j + s];
            __syncthreads();
        }
        float nrm = sqrtf(red[0]) + 1e-12f;
        __syncthreads();
        simn[j*NEXP + e] = v / nrm;
    }
}

// ---------- fp32 GEMM (projection only): C = A@B + bias ----------
__global__ __launch_bounds__(256)
void pgemm_k(const float* __restrict__ A, const float* __restrict__ B,
             const float* __restrict__ bias, float* __restrict__ Cout,
             int Kd, int Nd)
{
    const int row0 = blockIdx.y * 128, col0 = blockIdx.x * 128;
    __shared__ float As[8][128];
    __shared__ float Bs[8][128];
    const int t  = threadIdx.x;
    const int am = t >> 1, ak = (t & 1) * 4;
    const int bk = t >> 5, bn = (t & 31) * 4;
    const long asrc = (long)(row0 + am) * Kd;
    const int tm = (t & 15) * 8, tn = (t >> 4) * 8;
    float acc[8][8];
    #pragma unroll
    for (int i = 0; i < 8; i++)
        #pragma unroll
        for (int j = 0; j < 8; j++) acc[i][j] = 0.f;

    for (int k0 = 0; k0 < Kd; k0 += 8){
        __syncthreads();
        float4 av = *(const float4*)(A + asrc + k0 + ak);
        As[ak+0][am] = av.x; As[ak+1][am] = av.y; As[ak+2][am] = av.z; As[ak+3][am] = av.w;
        float4 bv = *(const float4*)(B + (long)(k0 + bk) * Nd + col0 + bn);
        *(float4*)&Bs[bk][bn] = bv;
        __syncthreads();
        #pragma unroll
        for (int kk = 0; kk < 8; kk++){
            float a[8], b[8];
            *(float4*)(a)   = *(const float4*)&As[kk][tm];
            *(float4*)(a+4) = *(const float4*)&As[kk][tm+4];
            *(float4*)(b)   = *(const float4*)&Bs[kk][tn];
            *(float4*)(b+4) = *(const float4*)&Bs[kk][tn+4];
            #pragma unroll
            for (int i = 0; i < 8; i++)
                #pragma unroll
                for (int j = 0; j < 8; j++)
                    acc[i][j] = fmaf(a[i], b[j], acc[i][j]);
        }
    }
    float bb[8];
    #pragma unroll
    for (int j = 0; j < 8; j++) bb[j] = bias[col0 + tn + j];
    #pragma unroll
    for (int i = 0; i < 8; i++){
        float* cp = Cout + (long)(row0 + tm + i) * Nd + col0 + tn;
        float4 f0, f1;
        f0.x = acc[i][0]+bb[0]; f0.y = acc[i][1]+bb[1]; f0.z = acc[i][2]+bb[2]; f0.w = acc[i][3]+bb[3];
        f1.x = acc[i][4]+bb[4]; f1.y = acc[i][5]+bb[5]; f1.z = acc[i][6]+bb[6]; f1.w = acc[i][7]+bb[7];
        *(float4*)cp = f0; *(float4*)(cp + 4) = f1;
    }
}

// ---------- bf16 MFMA GEMM, 128x128 tile, BK=32, 4 waves x (4x4 16x16 frags) ----------
// ASRC: 0 = fp32 source (convert on stage), 1 = bf16 source
// BSRC: 0 = fp32 weights (convert on stage), 1 = bf16 weights
// OMODE: 1 = bf16 store + ReLU (h), 3 = non-atomic scatter-add into out (y)
template<int ASRC, bool GATHER, int BSRC, int OMODE>
__global__ __launch_bounds__(256)
void mgemm_k(const void* __restrict__ Av, const void* __restrict__ Bv,
             const float* __restrict__ bias, void* __restrict__ Cout,
             int Kd, int Nd,
             const int* __restrict__ rowidx, const int* __restrict__ otok,
             const float* __restrict__ gs, const int* __restrict__ cntp, int cnti)
{
    const int row0 = blockIdx.y * 128, col0 = blockIdx.x * 128;
    int limit = cntp[cnti]; if (limit > CAP) limit = CAP;
    if (row0 >= limit) return;

    __shared__ short As[128][40];   // [m][k], 80B row stride (16B-aligned, bank-spread)
    __shared__ short Bs[128][40];   // [n][k]

    const int t = threadIdx.x;
    // A staging: thread -> row t>>1, k-halves of 16
    const int sar = t >> 1, sac = (t & 1) * 16;
    long abase;
    {
        int arow = row0 + sar;
        int gi = arow;
        if (GATHER) gi = (arow < limit) ? rowidx[arow] : 0;
        abase = (long)gi * Kd;
    }
    // B staging: thread -> 4 cols (n) x 4 rows (k)
    const int sbn = (t & 31) * 4, sbk = (t >> 5) * 4;

    const int l = t & 63, w = t >> 6;
    const int wm = (w >> 1) * 64, wn = (w & 1) * 64;
    const int fr = l & 15, fk = l >> 4;
    const int koff = fk * 8, fk4 = fk * 4;

    f32x4 acc[4][4];
    #pragma unroll
    for (int i = 0; i < 4; i++)
        #pragma unroll
        for (int j = 0; j < 4; j++) acc[i][j] = (f32x4){0.f, 0.f, 0.f, 0.f};

    for (int k0 = 0; k0 < Kd; k0 += 32){
        __syncthreads();
        // ---- stage A tile [128][32] ----
        if (ASRC == 0){
            const float* ap = (const float*)Av + abase + k0 + sac;
            float4 f0 = *(const float4*)(ap);
            float4 f1 = *(const float4*)(ap + 4);
            float4 f2 = *(const float4*)(ap + 8);
            float4 f3 = *(const float4*)(ap + 12);
            *(short4v*)&As[sar][sac+ 0] = (short4v){(short)f2bf(f0.x),(short)f2bf(f0.y),(short)f2bf(f0.z),(short)f2bf(f0.w)};
            *(short4v*)&As[sar][sac+ 4] = (short4v){(short)f2bf(f1.x),(short)f2bf(f1.y),(short)f2bf(f1.z),(short)f2bf(f1.w)};
            *(short4v*)&As[sar][sac+ 8] = (short4v){(short)f2bf(f2.x),(short)f2bf(f2.y),(short)f2bf(f2.z),(short)f2bf(f2.w)};
            *(short4v*)&As[sar][sac+12] = (short4v){(short)f2bf(f3.x),(short)f2bf(f3.y),(short)f2bf(f3.z),(short)f2bf(f3.w)};
        } else {
            const unsigned short* ap = (const unsigned short*)Av + abase + k0 + sac;
            uint4 u0 = *(const uint4*)(ap);
            uint4 u1 = *(const uint4*)(ap + 8);
            *(uint4*)&As[sar][sac + 0] = u0;
            *(uint4*)&As[sar][sac + 8] = u1;
        }
        // ---- stage B tile transposed -> Bs[n][k] ----
        if (BSRC == 0){
            const float* bp = (const float*)Bv;
            float rr[4][4];
            #pragma unroll
            for (int kki = 0; kki < 4; kki++){
                float4 f = *(const float4*)(bp + (long)(k0 + sbk + kki) * Nd + col0 + sbn);
                rr[kki][0] = f.x; rr[kki][1] = f.y; rr[kki][2] = f.z; rr[kki][3] = f.w;
            }
            #pragma unroll
            for (int j = 0; j < 4; j++)
                *(short4v*)&Bs[sbn + j][sbk] =
                    (short4v){(short)f2bf(rr[0][j]),(short)f2bf(rr[1][j]),(short)f2bf(rr[2][j]),(short)f2bf(rr[3][j])};
        } else {
            const unsigned short* bp = (const unsigned short*)Bv;
            short4v rr[4];
            #pragma unroll
            for (int kki = 0; kki < 4; kki++)
                rr[kki] = *(const short4v*)(bp + (long)(k0 + sbk + kki) * Nd + col0 + sbn);
            #pragma unroll
            for (int j = 0; j < 4; j++)
                *(short4v*)&Bs[sbn + j][sbk] = (short4v){rr[0][j], rr[1][j], rr[2][j], rr[3][j]};
        }
        __syncthreads();
        // ---- fragments + MFMA ----
        bf16x8 af[4], bf[4];
        #pragma unroll
        for (int i = 0; i < 4; i++) af[i] = *(const bf16x8*)&As[wm + i*16 + fr][koff];
        #pragma unroll
        for (int j = 0; j < 4; j++) bf[j] = *(const bf16x8*)&Bs[wn + j*16 + fr][koff];
        #pragma unroll
        for (int i = 0; i < 4; i++)
            #pragma unroll
            for (int j = 0; j < 4; j++)
                acc[i][j] = __builtin_amdgcn_mfma_f32_16x16x32_bf16(af[i], bf[j], acc[i][j], 0, 0, 0);
    }

    // ---- epilogue ----
    float bb[4];
    #pragma unroll
    for (int j = 0; j < 4; j++) bb[j] = bias[col0 + wn + j*16 + fr];
    #pragma unroll
    for (int i = 0; i < 4; i++){
        #pragma unroll
        for (int reg = 0; reg < 4; reg++){
            int r = row0 + wm + i*16 + fk4 + reg;
            if (r < limit){
                if (OMODE == 1){
                    unsigned short* hp = (unsigned short*)Cout + (long)r * Nd;
                    #pragma unroll
                    for (int j = 0; j < 4; j++){
                        float v = acc[i][j][reg] + bb[j];
                        v = fmaxf(v, 0.f);
                        hp[col0 + wn + j*16 + fr] = f2bf(v);
                    }
                } else {
                    int tk = otok[r];
                    float g = gs[r];
                    float* op = (float*)Cout + (long)tk * DDIM;
                    #pragma unroll
                    for (int j = 0; j < 4; j++){
                        float v = acc[i][j][reg] + bb[j];
                        op[col0 + wn + j*16 + fr] += g * v;   // race-free: rows are distinct tokens
                    }
                }
            }
        }
    }
}

// ---------- gate: one wave per token ----------
__global__ __launch_bounds__(256)
void gate_k(const float* __restrict__ P, const float* __restrict__ simn,
            const float* __restrict__ temp, int mode, const int* __restrict__ label,
            int n0, int* __restrict__ idx, float* __restrict__ gw)
{
    int gtid = blockIdx.x * 256 + threadIdx.x;
    int local = gtid >> 6, lane = gtid & 63;
    int n = n0 + local;
    const float* p = P + (long)local * PROJ;
    float v[4];
    #pragma unroll
    for (int r = 0; r < 4; r++) v[r] = p[lane + 64*r];
    float ss = v[0]*v[0] + v[1]*v[1] + v[2]*v[2] + v[3]*v[3];
    float dots[8];
    #pragma unroll
    for (int e = 0; e < 8; e++){
        float d = 0.f;
        #pragma unroll
        for (int r = 0; r < 4; r++) d += v[r] * simn[(lane + 64*r)*NEXP + e];
        dots[e] = d;
    }
    ss = wred(ss);
    #pragma unroll
    for (int e = 0; e < 8; e++) dots[e] = wred(dots[e]);
    if (lane == 0){
        float scale = expf(fminf(temp[0], LOG100));
        float inv = scale / (sqrtf(ss) + 1e-12f);
        float l[8], mx = -1e30f;
        #pragma unroll
        for (int e = 0; e < 8; e++){ l[e] = dots[e] * inv; mx = fmaxf(mx, l[e]); }
        float g[8], s = 0.f;
        #pragma unroll
        for (int e = 0; e < 8; e++){ g[e] = expf(l[e] - mx); s += g[e]; }
        #pragma unroll
        for (int e = 0; e < 8; e++) g[e] /= s;
        int e0 = 0; float b0 = g[0];
        #pragma unroll
        for (int e = 1; e < 8; e++) if (g[e] > b0){ b0 = g[e]; e0 = e; }
        int e1 = (e0 == 0) ? 1 : 0; float b1v = g[e1];
        #pragma unroll
        for (int e = 0; e < 8; e++) if (e != e0 && g[e] > b1v){ b1v = g[e]; e1 = e; }
        float maskv = (mode == 0) ? 1.f : ((label[n] == mode - 1) ? 1.f : 0.f);
        float s2 = b0 + b1v + 1e-9f;
        gw[2*n]   = b0 / s2 * maskv;
        gw[2*n+1] = b1v / s2 * maskv;
        idx[2*n]   = e0;
        idx[2*n+1] = e1;
    }
}

// ---------- ranking phase 1: per-block expert counts ----------
__global__ __launch_bounds__(1024)
void rank_count_k(const int* __restrict__ idx, const int* __restrict__ label, int mode,
                  int* __restrict__ bcnt)
{
    __shared__ int c[NEXP];
    int t = threadIdx.x;
    if (t < NEXP) c[t] = 0;
    __syncthreads();
    int s = blockIdx.x * 1024 + t;
    int n = s >> 1;
    int e = idx[s];
    bool valid = (mode == 0) || (label[n] == mode - 1);
    if (valid) atomicAdd(&c[e], 1);
    __syncthreads();
    if (t < NEXP) bcnt[blockIdx.x * NEXP + t] = c[t];
}

// ---------- ranking phase 2: exclusive scan over blocks ----------
__global__ void rank_scan_k(const int* __restrict__ bcnt, int* __restrict__ boff,
                            int* __restrict__ cntk)
{
    int e = threadIdx.x;
    if (e < NEXP){
        int run = 0;
        for (int b = 0; b < NSLOT/1024; b++){
            boff[b * NEXP + e] = run;
            run += bcnt[b * NEXP + e];
        }
        cntk[e] = run < CAP ? run : CAP;
    }
}

// ---------- ranking phase 3: assign positions, emit tok + gate per slot ----------
__global__ __launch_bounds__(1024)
void rank_assign_k(const int* __restrict__ idx, const int* __restrict__ label, int mode,
                   const int* __restrict__ boff, const float* __restrict__ gw,
                   const float* __restrict__ dscale, int use_scale,
                   int* __restrict__ tok_of, float* __restrict__ gs_of)
{
    __shared__ int wcnt[16][NEXP];
    __shared__ int woff[16][NEXP];
    int t = threadIdx.x;
    int s = blockIdx.x * 1024 + t;
    int n = s >> 1;
    int e = idx[s];
    bool valid = (mode == 0) || (label[n] == mode - 1);
    int w = t >> 6, lane = t & 63;
    unsigned long long lt = (lane == 0) ? 0ull : ((1ull << lane) - 1ull);
    int myrank = 0;
    #pragma unroll
    for (int ei = 0; ei < NEXP; ei++){
        unsigned long long bal = __ballot(valid && (e == ei));
        if (ei == e) myrank = __popcll(bal & lt);
        if (lane == 0) wcnt[w][ei] = __popcll(bal);
    }
    __syncthreads();
    if (t < NEXP){
        int run = boff[blockIdx.x * NEXP + t];
        for (int w2 = 0; w2 < 16; w2++){
            woff[w2][t] = run;
            run += wcnt[w2][t];
        }
    }
    __syncthreads();
    int pos = woff[w][e] + myrank;
    bool keep = valid && (pos < CAP);
    if (keep){
        float scale = use_scale ? dscale[0] : 1.f;
        tok_of[e * CAP + pos] = n;
        gs_of[e * CAP + pos] = gw[s] * scale;
    }
}

extern "C" void kernel_launch(void* const* d_in, const int* in_sizes, int n_in,
                              void* d_out, int out_size, void* d_ws, size_t ws_size,
                              hipStream_t stream)
{
    (void)in_sizes; (void)n_in; (void)out_size;
    const float* x      = (const float*)d_in[0];
    const int*   label  = (const int*)  d_in[1];
    const float* dscale = (const float*)d_in[2];
    float* out = (float*)d_out;

    // Workspace layout:
    //  [0, 32MB): BIG. P chunk (16MB f32) during gate phase; h (32MB bf16 [CAP,HDIM]) during FFN.
    //  optional: W1b (8MB bf16), W2b (8MB bf16)  -- only if ws_size allows
    //  then small buffers.
    const size_t BIGSZ = 33554432L;
    const size_t WBSZ  = (size_t)NEXP * DDIM * HDIM * 2;  // 8MB each
    const size_t smallsz = (size_t)PROJ*NEXP*4 + (size_t)NSLOT*4*2 +
                           (size_t)NEXP*CAP*4*2 + (size_t)(NSLOT/1024)*NEXP*4*2 + 256;
    const bool useWb = ws_size >= BIGSZ + 2*WBSZ + smallsz;
    if (!useWb && ws_size < BIGSZ + smallsz) return;  // clean failure, not a fault

    char* ws = (char*)d_ws;
    float*          P  = (float*)ws;
    unsigned short* h  = (unsigned short*)ws;
    char* sm = ws + BIGSZ;
    unsigned short* W1b = nullptr;
    unsigned short* W2b = nullptr;
    if (useWb){
        W1b = (unsigned short*)sm; sm += WBSZ;
        W2b = (unsigned short*)sm; sm += WBSZ;
    }
    float* simn  = (float*)sm;  sm += PROJ*NEXP*4;
    int*   idx   = (int*)sm;    sm += (size_t)NSLOT*4;
    float* gw    = (float*)sm;  sm += (size_t)NSLOT*4;
    int*   tok   = (int*)sm;    sm += (size_t)NEXP*CAP*4;
    float* gslot = (float*)sm;  sm += (size_t)NEXP*CAP*4;
    int*   bcnt  = (int*)sm;    sm += (size_t)(NSLOT/1024)*NEXP*4;
    int*   boff  = (int*)sm;    sm += (size_t)(NSLOT/1024)*NEXP*4;
    int*   cntk  = (int*)sm;    sm += 64;

    zero_k<<<dim3((NTOK*DDIM/4)/256), dim3(256), 0, stream>>>((float4*)out);

    const int WN4 = NEXP * DDIM * HDIM / 4;  // float4 count per weight tensor

    for (int m = 0; m < 3; m++){
        const float* Wp   = (const float*)d_in[3 + 8*m + 0];
        const float* bp   = (const float*)d_in[3 + 8*m + 1];
        const float* sim  = (const float*)d_in[3 + 8*m + 2];
        const float* temp = (const float*)d_in[3 + 8*m + 3];
        const float* W1   = (const float*)d_in[3 + 8*m + 4];
        const float* b1   = (const float*)d_in[3 + 8*m + 5];
        const float* W2   = (const float*)d_in[3 + 8*m + 6];
        const float* b2   = (const float*)d_in[3 + 8*m + 7];

        simn_k<<<dim3(1), dim3(256), 0, stream>>>(sim, simn);
        if (useWb){
            cvt_k<<<dim3((WN4+255)/256), dim3(256), 0, stream>>>((const float4*)W1, (ushort4*)W1b, WN4);
            cvt_k<<<dim3((WN4+255)/256), dim3(256), 0, stream>>>((const float4*)W2, (ushort4*)W2b, WN4);
        }

        // projection + gate, in token chunks (fp32 for top-k exactness)
        for (int c = 0; c < NTOK / TCHUNK; c++){
            pgemm_k<<<dim3(PROJ/128, TCHUNK/128), 256, 0, stream>>>(
                x + (long)c*TCHUNK*DDIM, Wp, bp, P, DDIM, PROJ);
            gate_k<<<dim3(TCHUNK/4), dim3(256), 0, stream>>>(
                P, simn, temp, m, label, c*TCHUNK, idx, gw);
        }

        rank_count_k<<<dim3(NSLOT/1024), dim3(1024), 0, stream>>>(idx, label, m, bcnt);
        rank_scan_k<<<dim3(1), dim3(64), 0, stream>>>(bcnt, boff, cntk);
        rank_assign_k<<<dim3(NSLOT/1024), dim3(1024), 0, stream>>>(
            idx, label, m, boff, gw, dscale, (m > 0) ? 1 : 0, tok, gslot);

        // per-expert FFN: h = relu(gather(x)@W1+b1) bf16, then out[tok] += g*(h@W2+b2)
        for (int e = 0; e < NEXP; e++){
            if (useWb){
                mgemm_k<0, true, 1, 1><<<dim3(HDIM/128, CAP/128), 256, 0, stream>>>(
                    x, W1b + (long)e*DDIM*HDIM, b1 + (long)e*HDIM, h,
                    DDIM, HDIM, tok + (long)e*CAP, nullptr, nullptr, cntk, e);
                mgemm_k<1, false, 1, 3><<<dim3(DDIM/128, CAP/128), 256, 0, stream>>>(
                    h, W2b + (long)e*HDIM*DDIM, b2 + (long)e*DDIM, out,
                    HDIM, DDIM, nullptr, tok + (long)e*CAP, gslot + (long)e*CAP, cntk, e);
            } else {
                mgemm_k<0, true, 0, 1><<<dim3(HDIM/128, CAP/128), 256, 0, stream>>>(
                    x, W1 + (long)e*DDIM*HDIM, b1 + (long)e*HDIM, h,
                    DDIM, HDIM, tok + (long)e*CAP, nullptr, nullptr, cntk, e);
                mgemm_k<1, false, 0, 3><<<dim3(DDIM/128, CAP/128), 256, 0, stream>>>(
                    h, W2 + (long)e*HDIM*DDIM, b2 + (long)e*DDIM, out,
                    HDIM, DDIM, nullptr, tok + (long)e*CAP, gslot + (long)e*CAP, cntk, e);
            }
        }
    }
}

// Round 4
// 2997.166 us; speedup vs baseline: 4.2628x; 1.2133x over previous
//
#include <hip/hip_runtime.h>

#define NTOK 65536
#define DDIM 512
#define HDIM 1024
#define NEXP 8
#define PROJ 256
#define CAP  16384
#define NSLOT (2*NTOK)
#define LOG100 4.605170185988091f

typedef __attribute__((ext_vector_type(8))) short bf16x8;
typedef __attribute__((ext_vector_type(4))) short short4v;
typedef __attribute__((ext_vector_type(4))) float f32x4;

// ---------- helpers ----------
__device__ inline float bf2f(unsigned short u){
    union { float f; unsigned int i; } c; c.i = ((unsigned int)u) << 16; return c.f;
}
__device__ inline unsigned short f2bf(float f){
    union { float f; unsigned int i; } c; c.f = f;
    unsigned int x = c.i;
    return (unsigned short)((x + 0x7fffu + ((x >> 16) & 1u)) >> 16); // RTNE
}

// async global->LDS, 16B per lane; LDS dest = wave-uniform base + lane*16
__device__ inline void gload16(const void* g, void* lds){
    __builtin_amdgcn_global_load_lds(
        (const __attribute__((address_space(1))) unsigned int*)g,
        (__attribute__((address_space(3))) unsigned int*)lds, 16, 0, 0);
}

__global__ void zero_k(float4* __restrict__ p){
    p[(long)blockIdx.x * 256 + threadIdx.x] = float4{0.f, 0.f, 0.f, 0.f};
}

// ---------- fp32 -> bf16 bulk convert ----------
__global__ void cvt_k(const float4* __restrict__ src, ushort4* __restrict__ dst, int n4){
    int i = blockIdx.x * 256 + threadIdx.x;
    if (i < n4){
        float4 f = src[i];
        ushort4 u; u.x = f2bf(f.x); u.y = f2bf(f.y); u.z = f2bf(f.z); u.w = f2bf(f.w);
        dst[i] = u;
    }
}

// ---------- tiled transpose + bf16 convert: out[c][r] = bf16(in[r][c]) ----------
__global__ __launch_bounds__(256)
void trans_k(const float* __restrict__ in, unsigned short* __restrict__ out,
             int R, int C, long stride)
{
    const float* ine = in + (long)blockIdx.z * stride;
    unsigned short* oute = out + (long)blockIdx.z * stride;
    __shared__ float tile[32][33];
    int tx = threadIdx.x, ty = threadIdx.y;   // (32,8)
    int rbase = blockIdx.y * 32, cbase = blockIdx.x * 32;
    #pragma unroll
    for (int i = 0; i < 4; i++)
        tile[ty + i*8][tx] = ine[(long)(rbase + ty + i*8) * C + cbase + tx];
    __syncthreads();
    #pragma unroll
    for (int i = 0; i < 4; i++)
        oute[(long)(cbase + ty + i*8) * R + rbase + tx] = f2bf(tile[tx][ty + i*8]);
}

// ---------- normalize sim columns ----------
__global__ void simn_k(const float* __restrict__ sim, float* __restrict__ simn){
    __shared__ float red[256];
    int j = threadIdx.x;
    for (int e = 0; e < NEXP; e++){
        float v = sim[j*NEXP + e];
        red[j] = v*v;
        __syncthreads();
        for (int s = 128; s > 0; s >>= 1){
            if (j < s) red[j] += red[j + s];
            __syncthreads();
        }
        float nrm = sqrtf(red[0]) + 1e-12f;
        __syncthreads();
        simn[j*NEXP + e] = v / nrm;
    }
}

// ---------- fused projection + gate: 32 tokens x full PROJ per block ----------
struct GateArgs { const float* Wp[3]; const float* bp[3]; const float* sn[3]; const float* tp[3]; };

__global__ __launch_bounds__(256)
void pgate_k(const float* __restrict__ x, const int* __restrict__ label,
             GateArgs ga, int* __restrict__ idx3, float* __restrict__ gw3)
{
    const int m = blockIdx.y;
    const int n0 = blockIdx.x * 32;
    const float* Wp = ga.Wp[m];

    __shared__ __align__(16) float As[16][32];
    __shared__ __align__(16) float Bs[16*256];   // float4 slots, XOR-swizzled
    __shared__ float Sn[PROJ*NEXP];
    __shared__ float Bp[PROJ];

    const int t = threadIdx.x;
    for (int i = t; i < PROJ*NEXP; i += 256) Sn[i] = ga.sn[m][i];
    Bp[t] = ga.bp[m][t];

    const int r = t >> 3;   // token row within tile
    const int c = t & 7;    // col group: cols c*32..c*32+31
    float acc[32];
    #pragma unroll
    for (int i = 0; i < 32; i++) acc[i] = 0.f;

    for (int k0 = 0; k0 < DDIM; k0 += 16){
        __syncthreads();
        {   // stage A (transposed): 32 rows x 16 k
            int rr = t >> 3, kk2 = (t & 7) * 2;
            float2 v = *(const float2*)(x + (long)(n0 + rr)*DDIM + k0 + kk2);
            As[kk2][rr] = v.x; As[kk2+1][rr] = v.y;
        }
        {   // stage B: 16 k-rows x 256 cols, swizzled float4 slots
            int kk = t >> 4, s0 = (t & 15) * 4;
            const float4* src = (const float4*)(Wp + (long)(k0 + kk)*PROJ) + s0;
            #pragma unroll
            for (int u = 0; u < 4; u++){
                int s = s0 + u;
                int p = (s & ~7) | ((s & 7) ^ ((s >> 3) & 7));
                ((float4*)Bs)[kk*64 + p] = src[u];
            }
        }
        __syncthreads();
        #pragma unroll
        for (int kk = 0; kk < 16; kk++){
            float a = As[kk][r];
            #pragma unroll
            for (int j = 0; j < 8; j++){
                float4 b = ((const float4*)Bs)[kk*64 + (c<<3) + (j ^ c)];
                acc[j*4+0] = fmaf(a, b.x, acc[j*4+0]);
                acc[j*4+1] = fmaf(a, b.y, acc[j*4+1]);
                acc[j*4+2] = fmaf(a, b.z, acc[j*4+2]);
                acc[j*4+3] = fmaf(a, b.w, acc[j*4+3]);
            }
        }
    }

    // epilogue: bias, partial l2/dot sums over this thread's 32 cols
    float ss = 0.f, dots[8];
    #pragma unroll
    for (int e = 0; e < 8; e++) dots[e] = 0.f;
    #pragma unroll
    for (int j = 0; j < 8; j++)
        #pragma unroll
        for (int u = 0; u < 4; u++){
            int col = c*32 + j*4 + u;
            float p = acc[j*4+u] + Bp[col];
            ss = fmaf(p, p, ss);
            #pragma unroll
            for (int e = 0; e < 8; e++) dots[e] = fmaf(p, Sn[col*NEXP + e], dots[e]);
        }
    #pragma unroll
    for (int o = 1; o < 8; o <<= 1){
        ss += __shfl_xor(ss, o, 64);
        #pragma unroll
        for (int e = 0; e < 8; e++) dots[e] += __shfl_xor(dots[e], o, 64);
    }
    if (c == 0){
        int n = n0 + r;
        float scale = expf(fminf(ga.tp[m][0], LOG100));
        float inv = scale / (sqrtf(ss) + 1e-12f);
        float l[8], mx = -1e30f;
        #pragma unroll
        for (int e = 0; e < 8; e++){ l[e] = dots[e] * inv; mx = fmaxf(mx, l[e]); }
        float g[8], s = 0.f;
        #pragma unroll
        for (int e = 0; e < 8; e++){ g[e] = expf(l[e] - mx); s += g[e]; }
        #pragma unroll
        for (int e = 0; e < 8; e++) g[e] /= s;
        int e0 = 0; float b0 = g[0];
        #pragma unroll
        for (int e = 1; e < 8; e++) if (g[e] > b0){ b0 = g[e]; e0 = e; }
        int e1 = (e0 == 0) ? 1 : 0; float b1v = g[e1];
        #pragma unroll
        for (int e = 0; e < 8; e++) if (e != e0 && g[e] > b1v){ b1v = g[e]; e1 = e; }
        float maskv = (m == 0) ? 1.f : ((label[n] == m - 1) ? 1.f : 0.f);
        float s2 = b0 + b1v + 1e-9f;
        long base = (long)m * NSLOT + 2*n;
        gw3[base]   = b0 / s2 * maskv;
        gw3[base+1] = b1v / s2 * maskv;
        idx3[base]   = e0;
        idx3[base+1] = e1;
    }
}

// ---------- bf16 MFMA GEMM, 128x128, BK=32, async LDS staging ----------
// AFP32: A is fp32 (reg-stage + convert); else bf16 via global_load_lds
// OMODE: 1 = bf16 store + ReLU (h); 3 = non-atomic scatter-add into out (y)
template<int AFP32, int GATHER, int OMODE>
__global__ __launch_bounds__(256)
void mgemm2_k(const void* __restrict__ Av, const unsigned short* __restrict__ BT,
              const float* __restrict__ bias, void* __restrict__ Cout,
              int Kd, int Nd,
              const int* __restrict__ rowidx, const int* __restrict__ otok,
              const float* __restrict__ gs, const int* __restrict__ cntp, int cnti)
{
    const int row0 = blockIdx.y * 128, col0 = blockIdx.x * 128;
    int limit = cntp[cnti]; if (limit > CAP) limit = CAP;
    if (row0 >= limit) return;

    __shared__ __align__(16) short As[128*32];
    __shared__ __align__(16) short Bs[128*32];

    const int t = threadIdx.x;
    const int w = t >> 6, l = t & 63;
    const int qrow = l >> 2;            // 0..15
    const int kc = (l & 3) * 8;         // k-offset in shorts (16B)

    // per-lane global row bases for async A (2 loads) and B (2 loads)
    long arowg[2];
    if (!AFP32){
        #pragma unroll
        for (int q = 0; q < 2; q++){
            int ar = row0 + w*32 + q*16 + qrow;
            int gi = ar;
            if (GATHER) gi = (ar < limit) ? rowidx[ar] : 0;
            arowg[q] = (long)gi * Kd;
        }
    }
    long browg[2];
    #pragma unroll
    for (int q = 0; q < 2; q++) browg[q] = (long)(col0 + w*32 + q*16 + qrow) * Kd;

    // fallback fp32 A reg-staging geometry
    const int sar = t >> 1, sac = (t & 1) * 16;
    long abase_f = 0;
    if (AFP32){
        int ar = row0 + sar;
        int gi = ar;
        if (GATHER) gi = (ar < limit) ? rowidx[ar] : 0;
        abase_f = (long)gi * Kd;
    }

    const int wm = (w >> 1) * 64, wn = (w & 1) * 64;
    const int fr = l & 15, fk = l >> 4;
    const int koff = fk * 8, fk4 = fk * 4;

    f32x4 acc[4][4];
    #pragma unroll
    for (int i = 0; i < 4; i++)
        #pragma unroll
        for (int j = 0; j < 4; j++) acc[i][j] = (f32x4){0.f, 0.f, 0.f, 0.f};

    for (int k0 = 0; k0 < Kd; k0 += 32){
        __syncthreads();
        if (AFP32){
            const float* ap = (const float*)Av + abase_f + k0 + sac;
            float4 f0 = *(const float4*)(ap);
            float4 f1 = *(const float4*)(ap + 4);
            float4 f2 = *(const float4*)(ap + 8);
            float4 f3 = *(const float4*)(ap + 12);
            short* dst = As + sar*32 + sac;
            *(short4v*)(dst+ 0) = (short4v){(short)f2bf(f0.x),(short)f2bf(f0.y),(short)f2bf(f0.z),(short)f2bf(f0.w)};
            *(short4v*)(dst+ 4) = (short4v){(short)f2bf(f1.x),(short)f2bf(f1.y),(short)f2bf(f1.z),(short)f2bf(f1.w)};
            *(short4v*)(dst+ 8) = (short4v){(short)f2bf(f2.x),(short)f2bf(f2.y),(short)f2bf(f2.z),(short)f2bf(f2.w)};
            *(short4v*)(dst+12) = (short4v){(short)f2bf(f3.x),(short)f2bf(f3.y),(short)f2bf(f3.z),(short)f2bf(f3.w)};
        } else {
            const unsigned short* ap = (const unsigned short*)Av;
            #pragma unroll
            for (int q = 0; q < 2; q++)
                gload16(ap + arowg[q] + k0 + kc, As + w*1024 + q*512);
        }
        #pragma unroll
        for (int q = 0; q < 2; q++)
            gload16(BT + browg[q] + k0 + kc, Bs + w*1024 + q*512);
        __syncthreads();

        bf16x8 af[4], bfv[4];
        #pragma unroll
        for (int i = 0; i < 4; i++) af[i]  = *(const bf16x8*)&As[(wm + i*16 + fr)*32 + koff];
        #pragma unroll
        for (int j = 0; j < 4; j++) bfv[j] = *(const bf16x8*)&Bs[(wn + j*16 + fr)*32 + koff];
        #pragma unroll
        for (int i = 0; i < 4; i++)
            #pragma unroll
            for (int j = 0; j < 4; j++)
                acc[i][j] = __builtin_amdgcn_mfma_f32_16x16x32_bf16(af[i], bfv[j], acc[i][j], 0, 0, 0);
    }

    float bb[4];
    #pragma unroll
    for (int j = 0; j < 4; j++) bb[j] = bias[col0 + wn + j*16 + fr];
    #pragma unroll
    for (int i = 0; i < 4; i++){
        #pragma unroll
        for (int reg = 0; reg < 4; reg++){
            int r = row0 + wm + i*16 + fk4 + reg;
            if (r < limit){
                if (OMODE == 1){
                    unsigned short* hp = (unsigned short*)Cout + (long)r * Nd;
                    #pragma unroll
                    for (int j = 0; j < 4; j++){
                        float v = acc[i][j][reg] + bb[j];
                        hp[col0 + wn + j*16 + fr] = f2bf(fmaxf(v, 0.f));
                    }
                } else {
                    int tk = otok[r];
                    float g = gs[r];
                    float* op = (float*)Cout + (long)tk * DDIM;
                    #pragma unroll
                    for (int j = 0; j < 4; j++){
                        float v = acc[i][j][reg] + bb[j];
                        op[col0 + wn + j*16 + fr] += g * v;   // race-free: distinct tokens per dispatch
                    }
                }
            }
        }
    }
}

// ---------- ranking ----------
__global__ __launch_bounds__(1024)
void rank_count_k(const int* __restrict__ idx, const int* __restrict__ label, int mode,
                  int* __restrict__ bcnt)
{
    __shared__ int c[NEXP];
    int t = threadIdx.x;
    if (t < NEXP) c[t] = 0;
    __syncthreads();
    int s = blockIdx.x * 1024 + t;
    int n = s >> 1;
    int e = idx[s];
    bool valid = (mode == 0) || (label[n] == mode - 1);
    if (valid) atomicAdd(&c[e], 1);
    __syncthreads();
    if (t < NEXP) bcnt[blockIdx.x * NEXP + t] = c[t];
}

__global__ void rank_scan_k(const int* __restrict__ bcnt, int* __restrict__ boff,
                            int* __restrict__ cntk)
{
    int e = threadIdx.x;
    if (e < NEXP){
        int run = 0;
        for (int b = 0; b < NSLOT/1024; b++){
            boff[b * NEXP + e] = run;
            run += bcnt[b * NEXP + e];
        }
        cntk[e] = run < CAP ? run : CAP;
    }
}

__global__ __launch_bounds__(1024)
void rank_assign_k(const int* __restrict__ idx, const int* __restrict__ label, int mode,
                   const int* __restrict__ boff, const float* __restrict__ gw,
                   const float* __restrict__ dscale, int use_scale,
                   int* __restrict__ tok_of, float* __restrict__ gs_of)
{
    __shared__ int wcnt[16][NEXP];
    __shared__ int woff[16][NEXP];
    int t = threadIdx.x;
    int s = blockIdx.x * 1024 + t;
    int n = s >> 1;
    int e = idx[s];
    bool valid = (mode == 0) || (label[n] == mode - 1);
    int w = t >> 6, lane = t & 63;
    unsigned long long lt = (lane == 0) ? 0ull : ((1ull << lane) - 1ull);
    int myrank = 0;
    #pragma unroll
    for (int ei = 0; ei < NEXP; ei++){
        unsigned long long bal = __ballot(valid && (e == ei));
        if (ei == e) myrank = __popcll(bal & lt);
        if (lane == 0) wcnt[w][ei] = __popcll(bal);
    }
    __syncthreads();
    if (t < NEXP){
        int run = boff[blockIdx.x * NEXP + t];
        for (int w2 = 0; w2 < 16; w2++){
            woff[w2][t] = run;
            run += wcnt[w2][t];
        }
    }
    __syncthreads();
    int pos = woff[w][e] + myrank;
    bool keep = valid && (pos < CAP);
    if (keep){
        float scale = use_scale ? dscale[0] : 1.f;
        tok_of[e * CAP + pos] = n;
        gs_of[e * CAP + pos] = gw[s] * scale;
    }
}

extern "C" void kernel_launch(void* const* d_in, const int* in_sizes, int n_in,
                              void* d_out, int out_size, void* d_ws, size_t ws_size,
                              hipStream_t stream)
{
    (void)in_sizes; (void)n_in; (void)out_size;
    const float* x      = (const float*)d_in[0];
    const int*   label  = (const int*)  d_in[1];
    const float* dscale = (const float*)d_in[2];
    float* out = (float*)d_out;

    // Workspace layout:
    //   h    : 32MB bf16 [CAP][HDIM]
    //   W1T  : 8MB  bf16 [E][HDIM][DDIM]  (transposed per model)
    //   W2T  : 8MB  bf16 [E][DDIM][HDIM]
    //   small buffers (~4MB)
    //   xb   : 64MB bf16 [NTOK][DDIM]  (optional, if ws allows)
    const size_t HSZ  = (size_t)CAP * HDIM * 2;
    const size_t WTSZ = (size_t)NEXP * DDIM * HDIM * 2;
    const size_t XBSZ = (size_t)NTOK * DDIM * 2;
    const size_t SMALL = (size_t)3*PROJ*NEXP*4 + (size_t)3*NSLOT*4*2 +
                         (size_t)NEXP*CAP*4*2 + (size_t)(NSLOT/1024)*NEXP*4*2 + 256;
    if (ws_size < HSZ + 2*WTSZ + SMALL) return;   // clean failure, not a fault
    const bool useXb = ws_size >= HSZ + 2*WTSZ + SMALL + XBSZ;

    char* p = (char*)d_ws;
    unsigned short* h   = (unsigned short*)p; p += HSZ;
    unsigned short* W1T = (unsigned short*)p; p += WTSZ;
    unsigned short* W2T = (unsigned short*)p; p += WTSZ;
    float* simn3 = (float*)p;  p += (size_t)3*PROJ*NEXP*4;
    int*   idx3  = (int*)p;    p += (size_t)3*NSLOT*4;
    float* gw3   = (float*)p;  p += (size_t)3*NSLOT*4;
    int*   tok   = (int*)p;    p += (size_t)NEXP*CAP*4;
    float* gslot = (float*)p;  p += (size_t)NEXP*CAP*4;
    int*   bcnt  = (int*)p;    p += (size_t)(NSLOT/1024)*NEXP*4;
    int*   boff  = (int*)p;    p += (size_t)(NSLOT/1024)*NEXP*4;
    int*   cntk  = (int*)p;    p += 64;
    unsigned short* xb = (unsigned short*)p;   // only touched when useXb

    zero_k<<<dim3((NTOK*DDIM/4)/256), dim3(256), 0, stream>>>((float4*)out);
    if (useXb)
        cvt_k<<<dim3(NTOK*DDIM/4/256), dim3(256), 0, stream>>>((const float4*)x, (ushort4*)xb, NTOK*DDIM/4);

    GateArgs ga;
    for (int m = 0; m < 3; m++){
        ga.Wp[m] = (const float*)d_in[3 + 8*m + 0];
        ga.bp[m] = (const float*)d_in[3 + 8*m + 1];
        ga.sn[m] = simn3 + (size_t)m * PROJ * NEXP;
        ga.tp[m] = (const float*)d_in[3 + 8*m + 3];
        simn_k<<<dim3(1), dim3(256), 0, stream>>>((const float*)d_in[3 + 8*m + 2],
                                                  simn3 + (size_t)m * PROJ * NEXP);
    }
    pgate_k<<<dim3(NTOK/32, 3), dim3(256), 0, stream>>>(x, label, ga, idx3, gw3);

    for (int m = 0; m < 3; m++){
        const float* W1 = (const float*)d_in[3 + 8*m + 4];
        const float* b1 = (const float*)d_in[3 + 8*m + 5];
        const float* W2 = (const float*)d_in[3 + 8*m + 6];
        const float* b2 = (const float*)d_in[3 + 8*m + 7];
        const int* idxm = idx3 + (size_t)m * NSLOT;
        const float* gwm = gw3 + (size_t)m * NSLOT;

        trans_k<<<dim3(HDIM/32, DDIM/32, NEXP), dim3(32,8), 0, stream>>>(
            W1, W1T, DDIM, HDIM, (long)DDIM*HDIM);
        trans_k<<<dim3(DDIM/32, HDIM/32, NEXP), dim3(32,8), 0, stream>>>(
            W2, W2T, HDIM, DDIM, (long)DDIM*HDIM);

        rank_count_k<<<dim3(NSLOT/1024), dim3(1024), 0, stream>>>(idxm, label, m, bcnt);
        rank_scan_k<<<dim3(1), dim3(64), 0, stream>>>(bcnt, boff, cntk);
        rank_assign_k<<<dim3(NSLOT/1024), dim3(1024), 0, stream>>>(
            idxm, label, m, boff, gwm, dscale, (m > 0) ? 1 : 0, tok, gslot);

        for (int e = 0; e < NEXP; e++){
            if (useXb)
                mgemm2_k<0, 1, 1><<<dim3(HDIM/128, CAP/128), 256, 0, stream>>>(
                    xb, W1T + (size_t)e*HDIM*DDIM, b1 + (size_t)e*HDIM, h,
                    DDIM, HDIM, tok + (size_t)e*CAP, nullptr, nullptr, cntk, e);
            else
                mgemm2_k<1, 1, 1><<<dim3(HDIM/128, CAP/128), 256, 0, stream>>>(
                    x, W1T + (size_t)e*HDIM*DDIM, b1 + (size_t)e*HDIM, h,
                    DDIM, HDIM, tok + (size_t)e*CAP, nullptr, nullptr, cntk, e);
            mgemm2_k<0, 0, 3><<<dim3(DDIM/128, CAP/128), 256, 0, stream>>>(
                h, W2T + (size_t)e*DDIM*HDIM, b2 + (size_t)e*DDIM, out,
                HDIM, DDIM, nullptr, tok + (size_t)e*CAP, gslot + (size_t)e*CAP, cntk, e);
        }
    }
}

// Round 5
// 2428.660 us; speedup vs baseline: 5.2606x; 1.2341x over previous
//
#include <hip/hip_runtime.h>

#define NTOK 65536
#define DDIM 512
#define HDIM 1024
#define NEXP 8
#define PROJ 256
#define CAP  16384
#define NSLOT (2*NTOK)
#define LOG100 4.605170185988091f

typedef __attribute__((ext_vector_type(8))) short bf16x8;
typedef __attribute__((ext_vector_type(4))) short short4v;
typedef __attribute__((ext_vector_type(4))) float f32x4;

// ---------- helpers ----------
__device__ inline float bf2f(unsigned short u){
    union { float f; unsigned int i; } c; c.i = ((unsigned int)u) << 16; return c.f;
}
__device__ inline unsigned short f2bf(float f){
    union { float f; unsigned int i; } c; c.f = f;
    unsigned int x = c.i;
    return (unsigned short)((x + 0x7fffu + ((x >> 16) & 1u)) >> 16); // RTNE
}
__device__ inline void gload16(const void* g, void* lds){
    __builtin_amdgcn_global_load_lds(
        (const __attribute__((address_space(1))) unsigned int*)g,
        (__attribute__((address_space(3))) unsigned int*)lds, 16, 0, 0);
}

__global__ void zero_k(float4* __restrict__ p){
    p[(long)blockIdx.x * 256 + threadIdx.x] = float4{0.f, 0.f, 0.f, 0.f};
}

__global__ void cvt_k(const float4* __restrict__ src, ushort4* __restrict__ dst, int n4){
    int i = blockIdx.x * 256 + threadIdx.x;
    if (i < n4){
        float4 f = src[i];
        ushort4 u; u.x = f2bf(f.x); u.y = f2bf(f.y); u.z = f2bf(f.z); u.w = f2bf(f.w);
        dst[i] = u;
    }
}

// ---------- batched transpose+convert: z<8 -> W1 expert z, z>=8 -> W2 expert z-8 ----------
__global__ __launch_bounds__(256)
void trans2_k(const float* __restrict__ W1, const float* __restrict__ W2,
              unsigned short* __restrict__ W1T, unsigned short* __restrict__ W2T)
{
    int z = blockIdx.z;
    const float* in; unsigned short* out; int R, C;
    if (z < 8){ in = W1 + (size_t)z*DDIM*HDIM; out = W1T + (size_t)z*DDIM*HDIM; R = DDIM; C = HDIM; }
    else      { in = W2 + (size_t)(z-8)*DDIM*HDIM; out = W2T + (size_t)(z-8)*DDIM*HDIM; R = HDIM; C = DDIM; }
    int rbase = blockIdx.y * 32, cbase = blockIdx.x * 32;
    if (rbase >= R || cbase >= C) return;
    __shared__ float tile[32][33];
    int tx = threadIdx.x, ty = threadIdx.y;   // (32,8)
    #pragma unroll
    for (int i = 0; i < 4; i++)
        tile[ty + i*8][tx] = in[(long)(rbase + ty + i*8) * C + cbase + tx];
    __syncthreads();
    #pragma unroll
    for (int i = 0; i < 4; i++)
        out[(long)(cbase + ty + i*8) * R + rbase + tx] = f2bf(tile[tx][ty + i*8]);
}

// ---------- normalize sim columns, batched over 3 models ----------
struct SimArgs { const float* sim[3]; };

__global__ void simn3_k(SimArgs sa, float* __restrict__ simn3){
    __shared__ float red[256];
    const float* sim = sa.sim[blockIdx.x];
    float* simn = simn3 + (size_t)blockIdx.x * PROJ * NEXP;
    int j = threadIdx.x;
    for (int e = 0; e < NEXP; e++){
        float v = sim[j*NEXP + e];
        red[j] = v*v;
        __syncthreads();
        for (int s = 128; s > 0; s >>= 1){
            if (j < s) red[j] += red[j + s];
            __syncthreads();
        }
        float nrm = sqrtf(red[0]) + 1e-12f;
        __syncthreads();
        simn[j*NEXP + e] = v / nrm;
    }
}

// ---------- fused projection + gate v2: 64 tokens x 256 cols, BK=32, 4x16 thread tile ----------
struct GateArgs { const float* Wp[3]; const float* bp[3]; const float* sn[3]; const float* tp[3]; };

__global__ __launch_bounds__(256)
void pgate2_k(const float* __restrict__ x, const int* __restrict__ label,
              GateArgs ga, int* __restrict__ idx3, float* __restrict__ gw3)
{
    const int m = blockIdx.y;
    const int n0 = blockIdx.x * 64;
    const float* Wp = ga.Wp[m];

    __shared__ __align__(16) float As[32][64];     // [k][token] 8KB
    __shared__ __align__(16) float Bs[32][256];    // [k][col] as swizzled float4 slots, 32KB
    __shared__ float Sn[PROJ*NEXP];                // 8KB
    __shared__ float Bp[PROJ];                     // 1KB

    const int t = threadIdx.x;
    for (int i = t; i < PROJ*NEXP; i += 256) Sn[i] = ga.sn[m][i];
    Bp[t] = ga.bp[m][t];

    const int tn = t & 15;      // col group: cols tn*16 .. tn*16+15
    const int tmq = t >> 4;     // token group: tokens tmq*4 .. tmq*4+3
    int bidx[4];
    #pragma unroll
    for (int j = 0; j < 4; j++){ int s = tn*4 + j; bidx[j] = s ^ ((s >> 3) & 7); }

    // staging geometry
    const int arow = t & 63, akc = (t >> 6) * 8;
    const float* aptr = x + (long)(n0 + arow) * DDIM + akc;
    const int bs = t & 63, bk0 = t >> 6;
    const int bphys = bs ^ ((bs >> 3) & 7);

    float acc[4][16];
    #pragma unroll
    for (int a = 0; a < 4; a++)
        #pragma unroll
        for (int i = 0; i < 16; i++) acc[a][i] = 0.f;

    for (int k0 = 0; k0 < DDIM; k0 += 32){
        __syncthreads();
        {   // A stage: transposed scalar writes, 2 lanes/bank (free)
            float4 a0 = *(const float4*)(aptr + k0);
            float4 a1 = *(const float4*)(aptr + k0 + 4);
            As[akc+0][arow] = a0.x; As[akc+1][arow] = a0.y;
            As[akc+2][arow] = a0.z; As[akc+3][arow] = a0.w;
            As[akc+4][arow] = a1.x; As[akc+5][arow] = a1.y;
            As[akc+6][arow] = a1.z; As[akc+7][arow] = a1.w;
        }
        #pragma unroll
        for (int i = 0; i < 8; i++){   // B stage: coalesced rows, swizzled slots
            int kk = bk0 + i*4;
            float4 bv = *(const float4*)(Wp + (long)(k0 + kk) * PROJ + bs*4);
            *(float4*)&Bs[kk][bphys*4] = bv;
        }
        __syncthreads();
        #pragma unroll
        for (int kk = 0; kk < 32; kk++){
            float4 a4 = *(const float4*)&As[kk][tmq*4];
            #pragma unroll
            for (int j = 0; j < 4; j++){
                float4 b = *(const float4*)&Bs[kk][bidx[j]*4];
                #pragma unroll
                for (int ai = 0; ai < 4; ai++){
                    float av = (ai==0)?a4.x:(ai==1)?a4.y:(ai==2)?a4.z:a4.w;
                    acc[ai][j*4+0] = fmaf(av, b.x, acc[ai][j*4+0]);
                    acc[ai][j*4+1] = fmaf(av, b.y, acc[ai][j*4+1]);
                    acc[ai][j*4+2] = fmaf(av, b.z, acc[ai][j*4+2]);
                    acc[ai][j*4+3] = fmaf(av, b.w, acc[ai][j*4+3]);
                }
            }
        }
    }

    // epilogue: bias + per-thread partial l2/dot sums over 16 cols x 4 tokens
    float ss[4] = {0.f, 0.f, 0.f, 0.f};
    float dots[4][8];
    #pragma unroll
    for (int a = 0; a < 4; a++)
        #pragma unroll
        for (int e = 0; e < 8; e++) dots[a][e] = 0.f;

    #pragma unroll
    for (int j = 0; j < 4; j++)
        #pragma unroll
        for (int w = 0; w < 4; w++){
            int col = tn*16 + j*4 + w;
            float bias = Bp[col];
            float sn[8];
            *(float4*)(sn)   = *(const float4*)&Sn[col*8];
            *(float4*)(sn+4) = *(const float4*)&Sn[col*8+4];
            #pragma unroll
            for (int ai = 0; ai < 4; ai++){
                float p = acc[ai][j*4+w] + bias;
                ss[ai] = fmaf(p, p, ss[ai]);
                #pragma unroll
                for (int e = 0; e < 8; e++) dots[ai][e] = fmaf(p, sn[e], dots[ai][e]);
            }
        }
    #pragma unroll
    for (int o = 1; o <= 8; o <<= 1){
        #pragma unroll
        for (int ai = 0; ai < 4; ai++){
            ss[ai] += __shfl_xor(ss[ai], o, 64);
            #pragma unroll
            for (int e = 0; e < 8; e++) dots[ai][e] += __shfl_xor(dots[ai][e], o, 64);
        }
    }
    if (tn == 0){
        float scale = expf(fminf(ga.tp[m][0], LOG100));
        #pragma unroll
        for (int ai = 0; ai < 4; ai++){
            int n = n0 + tmq*4 + ai;
            float inv = scale / (sqrtf(ss[ai]) + 1e-12f);
            float l[8], mx = -1e30f;
            #pragma unroll
            for (int e = 0; e < 8; e++){ l[e] = dots[ai][e] * inv; mx = fmaxf(mx, l[e]); }
            float g[8], s = 0.f;
            #pragma unroll
            for (int e = 0; e < 8; e++){ g[e] = expf(l[e] - mx); s += g[e]; }
            #pragma unroll
            for (int e = 0; e < 8; e++) g[e] /= s;
            int e0 = 0; float b0 = g[0];
            #pragma unroll
            for (int e = 1; e < 8; e++) if (g[e] > b0){ b0 = g[e]; e0 = e; }
            int e1 = (e0 == 0) ? 1 : 0; float b1v = g[e1];
            #pragma unroll
            for (int e = 0; e < 8; e++) if (e != e0 && g[e] > b1v){ b1v = g[e]; e1 = e; }
            float maskv = (m == 0) ? 1.f : ((label[n] == m - 1) ? 1.f : 0.f);
            float s2 = b0 + b1v + 1e-9f;
            long base = (long)m * NSLOT + 2*n;
            gw3[base]   = b0 / s2 * maskv;
            gw3[base+1] = b1v / s2 * maskv;
            idx3[base]   = e0;
            idx3[base+1] = e1;
        }
    }
}

// ---------- bf16 MFMA GEMM core, 128x128, BK=32 ----------
// AFP32: A fp32 (reg-stage+convert) else bf16 via global_load_lds
// OMODE: 1 = bf16 store + ReLU; 3 = non-atomic fp32 scatter-add into out
template<int AFP32, int GATHER, int OMODE>
__device__ __forceinline__
void gemm_core(short* As, short* Bs,
               const void* __restrict__ Av, const unsigned short* __restrict__ BT,
               const float* __restrict__ bias, void* __restrict__ Cout,
               int Kd, int Nd, int row0, int col0, int limit,
               const int* __restrict__ rowidx, const int* __restrict__ otok,
               const float* __restrict__ gs)
{
    const int t = threadIdx.x;
    const int w = t >> 6, l = t & 63;
    const int qrow = l >> 2;
    const int kc = (l & 3) * 8;

    long arowg[2];
    if (!AFP32){
        #pragma unroll
        for (int q = 0; q < 2; q++){
            int ar = row0 + w*32 + q*16 + qrow;
            int gi = ar;
            if (GATHER) gi = (ar < limit) ? rowidx[ar] : 0;
            arowg[q] = (long)gi * Kd;
        }
    }
    long browg[2];
    #pragma unroll
    for (int q = 0; q < 2; q++) browg[q] = (long)(col0 + w*32 + q*16 + qrow) * Kd;

    const int sar = t >> 1, sac = (t & 1) * 16;
    long abase_f = 0;
    if (AFP32){
        int ar = row0 + sar;
        int gi = ar;
        if (GATHER) gi = (ar < limit) ? rowidx[ar] : 0;
        abase_f = (long)gi * Kd;
    }

    const int wm = (w >> 1) * 64, wn = (w & 1) * 64;
    const int fr = l & 15, fk = l >> 4;
    const int koff = fk * 8, fk4 = fk * 4;

    f32x4 acc[4][4];
    #pragma unroll
    for (int i = 0; i < 4; i++)
        #pragma unroll
        for (int j = 0; j < 4; j++) acc[i][j] = (f32x4){0.f, 0.f, 0.f, 0.f};

    for (int k0 = 0; k0 < Kd; k0 += 32){
        __syncthreads();
        if (AFP32){
            const float* ap = (const float*)Av + abase_f + k0 + sac;
            float4 f0 = *(const float4*)(ap);
            float4 f1 = *(const float4*)(ap + 4);
            float4 f2 = *(const float4*)(ap + 8);
            float4 f3 = *(const float4*)(ap + 12);
            short* dst = As + sar*32 + sac;
            *(short4v*)(dst+ 0) = (short4v){(short)f2bf(f0.x),(short)f2bf(f0.y),(short)f2bf(f0.z),(short)f2bf(f0.w)};
            *(short4v*)(dst+ 4) = (short4v){(short)f2bf(f1.x),(short)f2bf(f1.y),(short)f2bf(f1.z),(short)f2bf(f1.w)};
            *(short4v*)(dst+ 8) = (short4v){(short)f2bf(f2.x),(short)f2bf(f2.y),(short)f2bf(f2.z),(short)f2bf(f2.w)};
            *(short4v*)(dst+12) = (short4v){(short)f2bf(f3.x),(short)f2bf(f3.y),(short)f2bf(f3.z),(short)f2bf(f3.w)};
        } else {
            const unsigned short* ap = (const unsigned short*)Av;
            #pragma unroll
            for (int q = 0; q < 2; q++)
                gload16(ap + arowg[q] + k0 + kc, As + w*1024 + q*512);
        }
        #pragma unroll
        for (int q = 0; q < 2; q++)
            gload16(BT + browg[q] + k0 + kc, Bs + w*1024 + q*512);
        __syncthreads();

        bf16x8 af[4], bfv[4];
        #pragma unroll
        for (int i = 0; i < 4; i++) af[i]  = *(const bf16x8*)&As[(wm + i*16 + fr)*32 + koff];
        #pragma unroll
        for (int j = 0; j < 4; j++) bfv[j] = *(const bf16x8*)&Bs[(wn + j*16 + fr)*32 + koff];
        #pragma unroll
        for (int i = 0; i < 4; i++)
            #pragma unroll
            for (int j = 0; j < 4; j++)
                acc[i][j] = __builtin_amdgcn_mfma_f32_16x16x32_bf16(af[i], bfv[j], acc[i][j], 0, 0, 0);
    }

    float bb[4];
    #pragma unroll
    for (int j = 0; j < 4; j++) bb[j] = bias[col0 + wn + j*16 + fr];
    #pragma unroll
    for (int i = 0; i < 4; i++){
        #pragma unroll
        for (int reg = 0; reg < 4; reg++){
            int r = row0 + wm + i*16 + fk4 + reg;
            if (r < limit){
                if (OMODE == 1){
                    unsigned short* hp = (unsigned short*)Cout + (long)r * Nd;
                    #pragma unroll
                    for (int j = 0; j < 4; j++){
                        float v = acc[i][j][reg] + bb[j];
                        hp[col0 + wn + j*16 + fr] = f2bf(fmaxf(v, 0.f));
                    }
                } else {
                    int tk = otok[r];
                    float g = gs[r];
                    float* op = (float*)Cout + (long)tk * DDIM;
                    #pragma unroll
                    for (int j = 0; j < 4; j++){
                        float v = acc[i][j][reg] + bb[j];
                        op[col0 + wn + j*16 + fr] += g * v;   // race-free: one expert per dispatch role
                    }
                }
            }
        }
    }
}

template<int AFP32, int GATHER, int OMODE>
__global__ __launch_bounds__(256)
void mgemm2_k(const void* __restrict__ Av, const unsigned short* __restrict__ BT,
              const float* __restrict__ bias, void* __restrict__ Cout,
              int Kd, int Nd,
              const int* __restrict__ rowidx, const int* __restrict__ otok,
              const float* __restrict__ gs, const int* __restrict__ cntp, int cnti)
{
    __shared__ __align__(16) short As[128*32];
    __shared__ __align__(16) short Bs[128*32];
    int limit = cntp[cnti]; if (limit > CAP) limit = CAP;
    int row0 = blockIdx.y * 128, col0 = blockIdx.x * 128;
    if (row0 >= limit) return;
    gemm_core<AFP32, GATHER, OMODE>(As, Bs, Av, BT, bias, Cout, Kd, Nd,
                                    row0, col0, limit, rowidx, otok, gs);
}

// ---------- pipelined dual-role FFN step: blocks x<8 do h-GEMM(eh), x>=8 do y-GEMM(eh-1) ----------
template<int AFP32>
__global__ __launch_bounds__(256)
void ffn_k(const void* __restrict__ xsrc,
           const unsigned short* __restrict__ W1T, const float* __restrict__ b1,
           const unsigned short* __restrict__ W2T, const float* __restrict__ b2,
           unsigned short* __restrict__ h0, unsigned short* __restrict__ h1,
           float* __restrict__ out,
           const int* __restrict__ tok, const float* __restrict__ gslot,
           const int* __restrict__ cntk, int eh)
{
    __shared__ __align__(16) short As[128*32];
    __shared__ __align__(16) short Bs[128*32];
    const int bx = blockIdx.x, row0 = blockIdx.y * 128;
    if (bx < 8){
        if (eh > 7) return;
        int limit = cntk[eh]; if (limit > CAP) limit = CAP;
        if (row0 >= limit) return;
        unsigned short* hd = (eh & 1) ? h1 : h0;
        gemm_core<AFP32, 1, 1>(As, Bs, xsrc, W1T + (size_t)eh*HDIM*DDIM, b1 + (size_t)eh*HDIM,
                               hd, DDIM, HDIM, row0, bx*128, limit,
                               tok + (size_t)eh*CAP, nullptr, nullptr);
    } else {
        int ey = eh - 1; if (ey < 0) return;
        int limit = cntk[ey]; if (limit > CAP) limit = CAP;
        if (row0 >= limit) return;
        const unsigned short* hs = (ey & 1) ? h1 : h0;
        gemm_core<0, 0, 3>(As, Bs, hs, W2T + (size_t)ey*DDIM*HDIM, b2 + (size_t)ey*DDIM,
                           out, HDIM, DDIM, row0, (bx-8)*128, limit,
                           nullptr, tok + (size_t)ey*CAP, gslot + (size_t)ey*CAP);
    }
}

// ---------- ranking ----------
__global__ __launch_bounds__(1024)
void rank_count_k(const int* __restrict__ idx, const int* __restrict__ label, int mode,
                  int* __restrict__ bcnt)
{
    __shared__ int c[NEXP];
    int t = threadIdx.x;
    if (t < NEXP) c[t] = 0;
    __syncthreads();
    int s = blockIdx.x * 1024 + t;
    int n = s >> 1;
    int e = idx[s];
    bool valid = (mode == 0) || (label[n] == mode - 1);
    if (valid) atomicAdd(&c[e], 1);
    __syncthreads();
    if (t < NEXP) bcnt[blockIdx.x * NEXP + t] = c[t];
}

__global__ void rank_scan_k(const int* __restrict__ bcnt, int* __restrict__ boff,
                            int* __restrict__ cntk)
{
    int e = threadIdx.x;
    if (e < NEXP){
        int run = 0;
        for (int b = 0; b < NSLOT/1024; b++){
            boff[b * NEXP + e] = run;
            run += bcnt[b * NEXP + e];
        }
        cntk[e] = run < CAP ? run : CAP;
    }
}

__global__ __launch_bounds__(1024)
void rank_assign_k(const int* __restrict__ idx, const int* __restrict__ label, int mode,
                   const int* __restrict__ boff, const float* __restrict__ gw,
                   const float* __restrict__ dscale, int use_scale,
                   int* __restrict__ tok_of, float* __restrict__ gs_of)
{
    __shared__ int wcnt[16][NEXP];
    __shared__ int woff[16][NEXP];
    int t = threadIdx.x;
    int s = blockIdx.x * 1024 + t;
    int n = s >> 1;
    int e = idx[s];
    bool valid = (mode == 0) || (label[n] == mode - 1);
    int w = t >> 6, lane = t & 63;
    unsigned long long lt = (lane == 0) ? 0ull : ((1ull << lane) - 1ull);
    int myrank = 0;
    #pragma unroll
    for (int ei = 0; ei < NEXP; ei++){
        unsigned long long bal = __ballot(valid && (e == ei));
        if (ei == e) myrank = __popcll(bal & lt);
        if (lane == 0) wcnt[w][ei] = __popcll(bal);
    }
    __syncthreads();
    if (t < NEXP){
        int run = boff[blockIdx.x * NEXP + t];
        for (int w2 = 0; w2 < 16; w2++){
            woff[w2][t] = run;
            run += wcnt[w2][t];
        }
    }
    __syncthreads();
    int pos = woff[w][e] + myrank;
    bool keep = valid && (pos < CAP);
    if (keep){
        float scale = use_scale ? dscale[0] : 1.f;
        tok_of[e * CAP + pos] = n;
        gs_of[e * CAP + pos] = gw[s] * scale;
    }
}

extern "C" void kernel_launch(void* const* d_in, const int* in_sizes, int n_in,
                              void* d_out, int out_size, void* d_ws, size_t ws_size,
                              hipStream_t stream)
{
    (void)in_sizes; (void)n_in; (void)out_size;
    const float* x      = (const float*)d_in[0];
    const int*   label  = (const int*)  d_in[1];
    const float* dscale = (const float*)d_in[2];
    float* out = (float*)d_out;

    const size_t HS   = (size_t)CAP * HDIM * 2;           // 32MB per h slot
    const size_t WT2  = (size_t)2 * NEXP * DDIM * HDIM * 2; // 16MB
    const size_t XB   = (size_t)NTOK * DDIM * 2;          // 64MB
    const size_t SMALL = (size_t)3*PROJ*NEXP*4 + (size_t)3*NSLOT*4*2 +
                         (size_t)NEXP*CAP*4*2 + (size_t)(NSLOT/1024)*NEXP*4*2 + 256;
    const size_t base = HS + WT2 + SMALL;                 // ~54.6MB (proven floor)

    bool pip = false, useXb = false;
    if      (ws_size >= base + HS + XB){ pip = true; useXb = true; }
    else if (ws_size >= base + XB)     { useXb = true; }
    else if (ws_size >= base + HS)     { pip = true; }
    else if (ws_size < base) return;   // clean failure, not a fault

    char* p = (char*)d_ws;
    unsigned short* h0  = (unsigned short*)p; p += HS;
    unsigned short* W1T = (unsigned short*)p; p += WT2/2;
    unsigned short* W2T = (unsigned short*)p; p += WT2/2;
    float* simn3 = (float*)p;  p += (size_t)3*PROJ*NEXP*4;
    int*   idx3  = (int*)p;    p += (size_t)3*NSLOT*4;
    float* gw3   = (float*)p;  p += (size_t)3*NSLOT*4;
    int*   tok   = (int*)p;    p += (size_t)NEXP*CAP*4;
    float* gslot = (float*)p;  p += (size_t)NEXP*CAP*4;
    int*   bcnt  = (int*)p;    p += (size_t)(NSLOT/1024)*NEXP*4;
    int*   boff  = (int*)p;    p += (size_t)(NSLOT/1024)*NEXP*4;
    int*   cntk  = (int*)p;    p += 256;
    unsigned short* h1 = nullptr;
    unsigned short* xb = nullptr;
    if (pip){ h1 = (unsigned short*)p; p += HS; }
    if (useXb){ xb = (unsigned short*)p; }

    zero_k<<<dim3((NTOK*DDIM/4)/256), dim3(256), 0, stream>>>((float4*)out);
    if (useXb)
        cvt_k<<<dim3(NTOK*DDIM/4/256), dim3(256), 0, stream>>>((const float4*)x, (ushort4*)xb, NTOK*DDIM/4);

    GateArgs ga; SimArgs sa;
    for (int m = 0; m < 3; m++){
        ga.Wp[m] = (const float*)d_in[3 + 8*m + 0];
        ga.bp[m] = (const float*)d_in[3 + 8*m + 1];
        ga.sn[m] = simn3 + (size_t)m * PROJ * NEXP;
        ga.tp[m] = (const float*)d_in[3 + 8*m + 3];
        sa.sim[m] = (const float*)d_in[3 + 8*m + 2];
    }
    simn3_k<<<dim3(3), dim3(256), 0, stream>>>(sa, simn3);
    pgate2_k<<<dim3(NTOK/64, 3), dim3(256), 0, stream>>>(x, label, ga, idx3, gw3);

    for (int m = 0; m < 3; m++){
        const float* W1 = (const float*)d_in[3 + 8*m + 4];
        const float* b1 = (const float*)d_in[3 + 8*m + 5];
        const float* W2 = (const float*)d_in[3 + 8*m + 6];
        const float* b2 = (const float*)d_in[3 + 8*m + 7];
        const int* idxm = idx3 + (size_t)m * NSLOT;
        const float* gwm = gw3 + (size_t)m * NSLOT;

        trans2_k<<<dim3(32, 32, 16), dim3(32,8), 0, stream>>>(W1, W2, W1T, W2T);

        rank_count_k<<<dim3(NSLOT/1024), dim3(1024), 0, stream>>>(idxm, label, m, bcnt);
        rank_scan_k<<<dim3(1), dim3(64), 0, stream>>>(bcnt, boff, cntk);
        rank_assign_k<<<dim3(NSLOT/1024), dim3(1024), 0, stream>>>(
            idxm, label, m, boff, gwm, dscale, (m > 0) ? 1 : 0, tok, gslot);

        if (pip){
            for (int eh = 0; eh <= 8; eh++){
                if (useXb)
                    ffn_k<0><<<dim3(12, CAP/128), 256, 0, stream>>>(
                        xb, W1T, b1, W2T, b2, h0, h1, out, tok, gslot, cntk, eh);
                else
                    ffn_k<1><<<dim3(12, CAP/128), 256, 0, stream>>>(
                        x, W1T, b1, W2T, b2, h0, h1, out, tok, gslot, cntk, eh);
            }
        } else {
            for (int e = 0; e < NEXP; e++){
                if (useXb)
                    mgemm2_k<0, 1, 1><<<dim3(HDIM/128, CAP/128), 256, 0, stream>>>(
                        xb, W1T + (size_t)e*HDIM*DDIM, b1 + (size_t)e*HDIM, h0,
                        DDIM, HDIM, tok + (size_t)e*CAP, nullptr, nullptr, cntk, e);
                else
                    mgemm2_k<1, 1, 1><<<dim3(HDIM/128, CAP/128), 256, 0, stream>>>(
                        x, W1T + (size_t)e*HDIM*DDIM, b1 + (size_t)e*HDIM, h0,
                        DDIM, HDIM, tok + (size_t)e*CAP, nullptr, nullptr, cntk, e);
                mgemm2_k<0, 0, 3><<<dim3(DDIM/128, CAP/128), 256, 0, stream>>>(
                    h0, W2T + (size_t)e*DDIM*HDIM, b2 + (size_t)e*DDIM, out,
                    HDIM, DDIM, nullptr, tok + (size_t)e*CAP, gslot + (size_t)e*CAP, cntk, e);
            }
        }
    }
}